// Round 11
// baseline (92.357 us; speedup 1.0000x reference)
//
#include <hip/hip_runtime.h>
#include <math.h>

// ---------------- problem constants ----------------
#define NROWS 32768   // B*T independent rows (alpha=exp(-50): scan decouples, verified R1)
#define NK 256        // IN_F
#define NF 256        // F
#define NT_SEQ 256    // T
#define MTILE 32      // rows per block (512 thr, 8 waves of 32 rows x 32 cols)
#define TAU 8e-3f     // bf16 vs fp64 ambiguity band (validated R10: absmax 0.0)

// Verified facts (R1/R3/R5..R10, absmax == 0.0):
//  * v_mem(t) == cur(t) exactly in the reference's own arithmetic.
//  * LN of binary s collapses: mu = k/256 exact, var = mu(1-mu).
//  * fp64 dot reproduces the np reference's spike decisions exactly.
//  * MFMA fragment mapping (A: row=lane&15, k=(lane>>4)*8+j; B: col=lane&15;
//    C/D: col=lane&15, row=(lane>>4)*4+reg) correct.
//  * bf16 single-comp GEMM + TAU=8e-3 + wave-parallel fp64 recheck: exact (R10).
// R11: (1) revert forced occupancy (R10's launch_bounds(512,6) -> VGPR 28 ->
// spill-starved MFMA, MfmaUtil 1.9%); (2) hoist each wave's whole B slice
// (32 cols x 256 K bf16 = 32 VGPRs) into registers BEFORE A staging, so the
// K-loop is pure ds_read_b128 + MFMA with no global latency and no barriers.

typedef __attribute__((ext_vector_type(4))) float f32x4;
typedef __attribute__((ext_vector_type(8))) short bf16x8;

__device__ __forceinline__ unsigned short bf16_rne(float f) {
    unsigned int u = __builtin_bit_cast(unsigned int, f);
    u += 0x7FFFu + ((u >> 16) & 1u);       // round-to-nearest-even
    return (unsigned short)(u >> 16);
}

// ---- k0: W -> bf16, MFMA-B-fragment order (layout verified R3..R10) ----
// wt[ks][chunk][col][j] shorts; ks stride 8192, chunk 2048, col 8.
__global__ void split_w(const float* __restrict__ W, unsigned short* __restrict__ wt) {
    const int k = blockIdx.x;       // 0..255
    const int col = threadIdx.x;    // 0..255
    const int ks = k >> 5, chunk = (k >> 3) & 3, j = k & 7;
    wt[(ks * 4 + chunk) * 2048 + col * 8 + j] = bf16_rne(W[k * NF + col]);
}

// ---- k1: bf16 GEMM (B in regs) + spike + exact recheck + closed-form LN ----
__global__ __launch_bounds__(512, 2)
void lif_main(const float* __restrict__ spikes,
              const float* __restrict__ W,
              const float* __restrict__ bias,
              const float* __restrict__ ln_scale,
              const float* __restrict__ ln_bias,
              const unsigned short* __restrict__ wt,
              float* __restrict__ out)
{
    // A panel: 32 rows x 256 k bf16, row stride 264 halfs (528 B ->
    // frag-read banks 4r mod 32: 2-way = free). 16.9 KB.
    __shared__ __align__(16) short alds[MTILE][264];
    __shared__ unsigned int bits[MTILE][8];    // 256-bit row masks
    __shared__ float rinv_s[MTILE], mu_s[MTILE];
    __shared__ unsigned int elist[256];        // in-band worklist
    __shared__ int ecnt;

    const int tid = threadIdx.x;
    const int lane = tid & 63;
    const int wid = tid >> 6;                  // 0..7: cols [wid*32, +32)
    const int row0 = blockIdx.x * MTILE;

    if (tid == 0) ecnt = 0;

    // ---- issue ALL B loads first (L2-resident; latency hides under staging) ----
    const int b_base = (lane >> 4) * 2048 + (wid * 32 + (lane & 15)) * 8;
    bf16x8 breg[8][2];                         // 32 VGPRs, static indices
    #pragma unroll
    for (int ks = 0; ks < 8; ++ks) {
        breg[ks][0] = *reinterpret_cast<const bf16x8*>(wt + ks * 8192 + b_base);
        breg[ks][1] = *reinterpret_cast<const bf16x8*>(wt + ks * 8192 + b_base + 128);
    }

    // ---- stage A panel as bf16 (one barrier) ----
    #pragma unroll
    for (int it = 0; it < 2; ++it) {
        const int idx = it * 512 + tid;
        const int r = idx >> 5, c8 = (idx & 31) * 8;
        const float* p = spikes + (size_t)(row0 + r) * NK + c8;
        const float4 u = *reinterpret_cast<const float4*>(p);
        const float4 v = *reinterpret_cast<const float4*>(p + 4);
        const unsigned int w0 = (unsigned int)bf16_rne(u.x) | ((unsigned int)bf16_rne(u.y) << 16);
        const unsigned int w1 = (unsigned int)bf16_rne(u.z) | ((unsigned int)bf16_rne(u.w) << 16);
        const unsigned int w2 = (unsigned int)bf16_rne(v.x) | ((unsigned int)bf16_rne(v.y) << 16);
        const unsigned int w3 = (unsigned int)bf16_rne(v.z) | ((unsigned int)bf16_rne(v.w) << 16);
        *reinterpret_cast<uint4*>(&alds[r][c8]) = make_uint4(w0, w1, w2, w3);
    }
    __syncthreads();

    // ---- barrier-free K loop: 8 steps x (2 ds_read_b128 + 4 MFMA) ----
    f32x4 acc[2][2];
    {
        const f32x4 z = {0.f, 0.f, 0.f, 0.f};
        acc[0][0] = z; acc[0][1] = z; acc[1][0] = z; acc[1][1] = z;
    }
    const int a_off = (lane & 15) * 264 + (lane >> 4) * 8;       // halfs
    const short* alds_flat = &alds[0][0];

    #pragma unroll
    for (int ks = 0; ks < 8; ++ks) {
        const bf16x8 a0 = *reinterpret_cast<const bf16x8*>(alds_flat + ks * 32 + a_off);
        const bf16x8 a1 = *reinterpret_cast<const bf16x8*>(alds_flat + 16 * 264 + ks * 32 + a_off);
        acc[0][0] = __builtin_amdgcn_mfma_f32_16x16x32_bf16(a0, breg[ks][0], acc[0][0], 0, 0, 0);
        acc[0][1] = __builtin_amdgcn_mfma_f32_16x16x32_bf16(a0, breg[ks][1], acc[0][1], 0, 0, 0);
        acc[1][0] = __builtin_amdgcn_mfma_f32_16x16x32_bf16(a1, breg[ks][0], acc[1][0], 0, 0, 0);
        acc[1][1] = __builtin_amdgcn_mfma_f32_16x16x32_bf16(a1, breg[ks][1], acc[1][1], 0, 0, 0);
    }

    // ---- decisions; in-band elements -> worklist ----
    unsigned int smask[2] = {0u, 0u};   // bit nt*4+reg
    #pragma unroll
    for (int mt = 0; mt < 2; ++mt)
        #pragma unroll
        for (int nt = 0; nt < 2; ++nt) {
            const int gcol = wid * 32 + nt * 16 + (lane & 15);
            const float bv = bias[gcol];
            #pragma unroll
            for (int reg = 0; reg < 4; ++reg) {
                const float v = acc[mt][nt][reg] + bv;
                if ((v - 0.5f) > 0.0f) smask[mt] |= 1u << (nt * 4 + reg);
                if (__builtin_expect(fabsf(v - 0.5f) < TAU, 0)) {
                    const int rl = mt * 16 + (lane >> 4) * 4 + reg;
                    const int ei = atomicAdd(&ecnt, 1);
                    if (ei < 256) elist[ei] = (unsigned int)((rl << 8) | gcol);
                }
            }
        }

    // ---- assemble row masks (one 32-bit word per row per wave) ----
    #pragma unroll
    for (int mt = 0; mt < 2; ++mt)
        #pragma unroll
        for (int reg = 0; reg < 4; ++reg) {
            const unsigned long long m0 = __ballot((smask[mt] >> (reg)) & 1u);
            const unsigned long long m1 = __ballot((smask[mt] >> (4 + reg)) & 1u);
            if (lane < 4) {
                const int g = lane;
                const unsigned int w =
                    (unsigned int)((m0 >> (g * 16)) & 0xFFFFull) |
                    ((unsigned int)((m1 >> (g * 16)) & 0xFFFFull) << 16);
                bits[mt * 16 + g * 4 + reg][wid] = w;
            }
        }
    __syncthreads();

    // ---- exact fp64 recheck of in-band elements (wave-parallel) ----
    const int ne = min(ecnt, 256);
    for (int e = wid; e < ne; e += 8) {
        const unsigned int pk = elist[e];
        const int rl = (int)(pk >> 8), gcol = (int)(pk & 255u);
        const float* sr = spikes + (size_t)(row0 + rl) * NK;
        const float* wc = W + gcol;
        const int k0 = lane * 4;
        const double p0 = (double)sr[k0 + 0] * (double)wc[(size_t)(k0 + 0) * NF];
        const double p1 = (double)sr[k0 + 1] * (double)wc[(size_t)(k0 + 1) * NF];
        const double p2 = (double)sr[k0 + 2] * (double)wc[(size_t)(k0 + 2) * NF];
        const double p3 = (double)sr[k0 + 3] * (double)wc[(size_t)(k0 + 3) * NF];
        double pl = (p0 + p1) + (p2 + p3);
        #pragma unroll
        for (int off = 32; off > 0; off >>= 1) pl += __shfl_down(pl, off);
        if (lane == 0) {
            const double vex = pl + (double)bias[gcol];
            const bool sex = (vex - 0.5) > 0.0;
            const bool spv = (bits[rl][gcol >> 5] >> (gcol & 31)) & 1u;
            if (sex != spv) atomicXor(&bits[rl][gcol >> 5], 1u << (gcol & 31));
        }
    }
    __syncthreads();

    // ---- per-row stats (identical double math to R1..R10) ----
    if (tid < MTILE) {
        int kc = 0;
        #pragma unroll
        for (int w = 0; w < 8; ++w) kc += __popc(bits[tid][w]);
        const double mu = (double)kc * (1.0 / 256.0);
        const double var = mu * (1.0 - mu);
        rinv_s[tid] = (float)(1.0 / sqrt(var + 1e-6));
        mu_s[tid] = (float)mu;
    }
    __syncthreads();

    // ---- LN epilogue + coalesced float4 store ----
    const int orow = tid >> 4;           // 0..31
    const int of0 = (tid & 15) * 4;      // 0..60
    const int grow = row0 + orow;
    const int t = grow & (NT_SEQ - 1);
    const float rinv = rinv_s[orow];
    const float muf = mu_s[orow];
    #pragma unroll
    for (int j = 0; j < 4; ++j) {
        const int f = of0 + j * 64;
        const unsigned int wb = bits[orow][f >> 5];
        const int sh = f & 31;
        const float4 g4 = *reinterpret_cast<const float4*>(&ln_scale[t * NF + f]);
        const float4 b4 = *reinterpret_cast<const float4*>(&ln_bias[t * NF + f]);
        float4 o;
        const float s0 = ((wb >> (sh + 0)) & 1u) ? 1.0f : 0.0f;
        const float s1 = ((wb >> (sh + 1)) & 1u) ? 1.0f : 0.0f;
        const float s2 = ((wb >> (sh + 2)) & 1u) ? 1.0f : 0.0f;
        const float s3 = ((wb >> (sh + 3)) & 1u) ? 1.0f : 0.0f;
        o.x = (s0 - muf) * rinv * g4.x + b4.x;
        o.y = (s1 - muf) * rinv * g4.y + b4.y;
        o.z = (s2 - muf) * rinv * g4.z + b4.z;
        o.w = (s3 - muf) * rinv * g4.w + b4.w;
        *reinterpret_cast<float4*>(&out[(size_t)grow * NF + f]) = o;
    }
}

extern "C" void kernel_launch(void* const* d_in, const int* in_sizes, int n_in,
                              void* d_out, int out_size, void* d_ws, size_t ws_size,
                              hipStream_t stream) {
    const float* spikes   = (const float*)d_in[0];
    const float* W        = (const float*)d_in[1];
    const float* bias     = (const float*)d_in[2];
    const float* ln_scale = (const float*)d_in[3];
    const float* ln_bias  = (const float*)d_in[4];
    float* out = (float*)d_out;
    unsigned short* wt = (unsigned short*)d_ws;   // 128 KB

    split_w<<<dim3(256), dim3(256), 0, stream>>>(W, wt);
    lif_main<<<dim3(NROWS / MTILE), dim3(512), 0, stream>>>(
        spikes, W, bias, ln_scale, ln_bias, wt, out);
}

// Round 12
// 39.609 us; speedup vs baseline: 2.3317x; 2.3317x over previous
//
#include <hip/hip_runtime.h>
#include <math.h>

// ---------------- problem constants ----------------
#define NROWS 32768   // B*T independent rows (alpha=exp(-50): scan decouples, verified R1)
#define NK 256        // IN_F
#define NF 256        // F
#define NT_SEQ 256    // T
#define MTILE 32      // rows per block (512 thr, 8 waves of 32 rows x 32 cols)
#define TAU 8e-3f     // bf16 vs fp64 ambiguity band (validated R10/R11: absmax 0.0)

// Verified facts (R1/R3/R5..R11, absmax == 0.0):
//  * v_mem(t) == cur(t) exactly in the reference's own arithmetic.
//  * LN of binary s collapses: mu = k/256 exact, var = mu(1-mu).
//  * fp64 dot (this exact summation order) reproduces np's spike decisions.
//  * MFMA fragment mapping (A: row=lane&15, k=(lane>>4)*8+j; B: col=lane&15;
//    C/D: col=lane&15, row=(lane>>4)*4+reg) correct.
//  * bf16 single-comp GEMM + TAU=8e-3 + wave-parallel fp64 recheck: exact (R10/R11).
// R12: the recheck was the 50-us sink (R5 4/block vs R10 62/block; W-column
// reads at stride 1KB = 256 cache lines/element). Fix: k0 also writes W^T
// (fp32) to ws; recheck reads spikes-row and W^T-row CONTIGUOUSLY. Same fp64
// math, same order -> same decisions.

typedef __attribute__((ext_vector_type(4))) float f32x4;
typedef __attribute__((ext_vector_type(8))) short bf16x8;

__device__ __forceinline__ unsigned short bf16_rne(float f) {
    unsigned int u = __builtin_bit_cast(unsigned int, f);
    u += 0x7FFFu + ((u >> 16) & 1u);       // round-to-nearest-even
    return (unsigned short)(u >> 16);
}

// ---- k0: W -> bf16 MFMA-B-fragment order (verified R3..R11) + fp32 W^T ----
// wt[ks][chunk][col][j] shorts; ks stride 8192, chunk 2048, col 8.
__global__ void prep_w(const float* __restrict__ W,
                       unsigned short* __restrict__ wt,
                       float* __restrict__ wtT) {
    const int k = blockIdx.x;       // 0..255
    const int col = threadIdx.x;    // 0..255
    const float w = W[k * NF + col];
    const int ks = k >> 5, chunk = (k >> 3) & 3, j = k & 7;
    wt[(ks * 4 + chunk) * 2048 + col * 8 + j] = bf16_rne(w);
    wtT[col * NK + k] = w;          // transpose (scattered write, tiny kernel)
}

// ---- k1: bf16 GEMM + spike + coalesced exact recheck + closed-form LN ----
__global__ __launch_bounds__(512)
void lif_main(const float* __restrict__ spikes,
              const float* __restrict__ bias,
              const float* __restrict__ ln_scale,
              const float* __restrict__ ln_bias,
              const unsigned short* __restrict__ wt,
              const float* __restrict__ wtT,
              float* __restrict__ out)
{
    // A panel: 32 rows x 256 k bf16, row stride 264 halfs. 16.9 KB.
    __shared__ __align__(16) short alds[MTILE][264];
    __shared__ unsigned int bits[MTILE][8];    // 256-bit row masks
    __shared__ float rinv_s[MTILE], mu_s[MTILE];
    __shared__ unsigned int elist[256];        // in-band worklist
    __shared__ int ecnt;

    const int tid = threadIdx.x;
    const int lane = tid & 63;
    const int wid = tid >> 6;                  // 0..7: cols [wid*32, +32)
    const int row0 = blockIdx.x * MTILE;

    if (tid == 0) ecnt = 0;

    // ---- stage A panel as bf16 (one barrier) ----
    #pragma unroll
    for (int it = 0; it < 2; ++it) {
        const int idx = it * 512 + tid;
        const int r = idx >> 5, c8 = (idx & 31) * 8;
        const float* p = spikes + (size_t)(row0 + r) * NK + c8;
        const float4 u = *reinterpret_cast<const float4*>(p);
        const float4 v = *reinterpret_cast<const float4*>(p + 4);
        const unsigned int w0 = (unsigned int)bf16_rne(u.x) | ((unsigned int)bf16_rne(u.y) << 16);
        const unsigned int w1 = (unsigned int)bf16_rne(u.z) | ((unsigned int)bf16_rne(u.w) << 16);
        const unsigned int w2 = (unsigned int)bf16_rne(v.x) | ((unsigned int)bf16_rne(v.y) << 16);
        const unsigned int w3 = (unsigned int)bf16_rne(v.z) | ((unsigned int)bf16_rne(v.w) << 16);
        *reinterpret_cast<uint4*>(&alds[r][c8]) = make_uint4(w0, w1, w2, w3);
    }
    __syncthreads();

    // ---- barrier-free K loop: 8 steps x (2 ds_read_b128 + 2 L2 loads + 4 MFMA) ----
    f32x4 acc[2][2];
    {
        const f32x4 z = {0.f, 0.f, 0.f, 0.f};
        acc[0][0] = z; acc[0][1] = z; acc[1][0] = z; acc[1][1] = z;
    }
    const int a_off = (lane & 15) * 264 + (lane >> 4) * 8;       // halfs
    const int b_base = (lane >> 4) * 2048 + (wid * 32 + (lane & 15)) * 8;
    const short* alds_flat = &alds[0][0];

    #pragma unroll
    for (int ks = 0; ks < 8; ++ks) {
        const bf16x8 b0 = *reinterpret_cast<const bf16x8*>(wt + ks * 8192 + b_base);
        const bf16x8 b1 = *reinterpret_cast<const bf16x8*>(wt + ks * 8192 + b_base + 128);
        const bf16x8 a0 = *reinterpret_cast<const bf16x8*>(alds_flat + ks * 32 + a_off);
        const bf16x8 a1 = *reinterpret_cast<const bf16x8*>(alds_flat + 16 * 264 + ks * 32 + a_off);
        acc[0][0] = __builtin_amdgcn_mfma_f32_16x16x32_bf16(a0, b0, acc[0][0], 0, 0, 0);
        acc[0][1] = __builtin_amdgcn_mfma_f32_16x16x32_bf16(a0, b1, acc[0][1], 0, 0, 0);
        acc[1][0] = __builtin_amdgcn_mfma_f32_16x16x32_bf16(a1, b0, acc[1][0], 0, 0, 0);
        acc[1][1] = __builtin_amdgcn_mfma_f32_16x16x32_bf16(a1, b1, acc[1][1], 0, 0, 0);
    }

    // ---- decisions; in-band elements -> worklist ----
    unsigned int smask[2] = {0u, 0u};   // bit nt*4+reg
    #pragma unroll
    for (int mt = 0; mt < 2; ++mt)
        #pragma unroll
        for (int nt = 0; nt < 2; ++nt) {
            const int gcol = wid * 32 + nt * 16 + (lane & 15);
            const float bv = bias[gcol];
            #pragma unroll
            for (int reg = 0; reg < 4; ++reg) {
                const float v = acc[mt][nt][reg] + bv;
                if ((v - 0.5f) > 0.0f) smask[mt] |= 1u << (nt * 4 + reg);
                if (__builtin_expect(fabsf(v - 0.5f) < TAU, 0)) {
                    const int rl = mt * 16 + (lane >> 4) * 4 + reg;
                    const int ei = atomicAdd(&ecnt, 1);
                    if (ei < 256) elist[ei] = (unsigned int)((rl << 8) | gcol);
                }
            }
        }

    // ---- assemble row masks (one 32-bit word per row per wave) ----
    #pragma unroll
    for (int mt = 0; mt < 2; ++mt)
        #pragma unroll
        for (int reg = 0; reg < 4; ++reg) {
            const unsigned long long m0 = __ballot((smask[mt] >> (reg)) & 1u);
            const unsigned long long m1 = __ballot((smask[mt] >> (4 + reg)) & 1u);
            if (lane < 4) {
                const int g = lane;
                const unsigned int w =
                    (unsigned int)((m0 >> (g * 16)) & 0xFFFFull) |
                    ((unsigned int)((m1 >> (g * 16)) & 0xFFFFull) << 16);
                bits[mt * 16 + g * 4 + reg][wid] = w;
            }
        }
    __syncthreads();

    // ---- exact fp64 recheck, now COALESCED via W^T (same math, same order) ----
    const int ne = min(ecnt, 256);
    for (int e = wid; e < ne; e += 8) {
        const unsigned int pk = elist[e];
        const int rl = (int)(pk >> 8), gcol = (int)(pk & 255u);
        const float* sr = spikes + (size_t)(row0 + rl) * NK;
        const float* wc = wtT + (size_t)gcol * NK;
        const int k0 = lane * 4;
        const float4 s4 = *reinterpret_cast<const float4*>(sr + k0);
        const float4 w4 = *reinterpret_cast<const float4*>(wc + k0);
        const double p0 = (double)s4.x * (double)w4.x;
        const double p1 = (double)s4.y * (double)w4.y;
        const double p2 = (double)s4.z * (double)w4.z;
        const double p3 = (double)s4.w * (double)w4.w;
        double pl = (p0 + p1) + (p2 + p3);
        #pragma unroll
        for (int off = 32; off > 0; off >>= 1) pl += __shfl_down(pl, off);
        if (lane == 0) {
            const double vex = pl + (double)bias[gcol];
            const bool sex = (vex - 0.5) > 0.0;
            const bool spv = (bits[rl][gcol >> 5] >> (gcol & 31)) & 1u;
            if (sex != spv) atomicXor(&bits[rl][gcol >> 5], 1u << (gcol & 31));
        }
    }
    __syncthreads();

    // ---- per-row stats (identical double math to R1..R11) ----
    if (tid < MTILE) {
        int kc = 0;
        #pragma unroll
        for (int w = 0; w < 8; ++w) kc += __popc(bits[tid][w]);
        const double mu = (double)kc * (1.0 / 256.0);
        const double var = mu * (1.0 - mu);
        rinv_s[tid] = (float)(1.0 / sqrt(var + 1e-6));
        mu_s[tid] = (float)mu;
    }
    __syncthreads();

    // ---- LN epilogue + coalesced float4 store ----
    const int orow = tid >> 4;           // 0..31
    const int of0 = (tid & 15) * 4;      // 0..60
    const int grow = row0 + orow;
    const int t = grow & (NT_SEQ - 1);
    const float rinv = rinv_s[orow];
    const float muf = mu_s[orow];
    #pragma unroll
    for (int j = 0; j < 4; ++j) {
        const int f = of0 + j * 64;
        const unsigned int wb = bits[orow][f >> 5];
        const int sh = f & 31;
        const float4 g4 = *reinterpret_cast<const float4*>(&ln_scale[t * NF + f]);
        const float4 b4 = *reinterpret_cast<const float4*>(&ln_bias[t * NF + f]);
        float4 o;
        const float s0 = ((wb >> (sh + 0)) & 1u) ? 1.0f : 0.0f;
        const float s1 = ((wb >> (sh + 1)) & 1u) ? 1.0f : 0.0f;
        const float s2 = ((wb >> (sh + 2)) & 1u) ? 1.0f : 0.0f;
        const float s3 = ((wb >> (sh + 3)) & 1u) ? 1.0f : 0.0f;
        o.x = (s0 - muf) * rinv * g4.x + b4.x;
        o.y = (s1 - muf) * rinv * g4.y + b4.y;
        o.z = (s2 - muf) * rinv * g4.z + b4.z;
        o.w = (s3 - muf) * rinv * g4.w + b4.w;
        *reinterpret_cast<float4*>(&out[(size_t)grow * NF + f]) = o;
    }
}

extern "C" void kernel_launch(void* const* d_in, const int* in_sizes, int n_in,
                              void* d_out, int out_size, void* d_ws, size_t ws_size,
                              hipStream_t stream) {
    const float* spikes   = (const float*)d_in[0];
    const float* W        = (const float*)d_in[1];
    const float* bias     = (const float*)d_in[2];
    const float* ln_scale = (const float*)d_in[3];
    const float* ln_bias  = (const float*)d_in[4];
    float* out = (float*)d_out;
    unsigned short* wt = (unsigned short*)d_ws;                 // 128 KB
    float* wtT = (float*)((char*)d_ws + 131072);                // 256 KB fp32 W^T

    prep_w<<<dim3(256), dim3(256), 0, stream>>>(W, wt, wtT);
    lif_main<<<dim3(NROWS / MTILE), dim3(512), 0, stream>>>(
        spikes, bias, ln_scale, ln_bias, wt, wtT, out);
}